// Round 1
// baseline (182.068 us; speedup 1.0000x reference)
//
#include <hip/hip_runtime.h>
#include <hip/hip_bf16.h>
#include <math.h>

typedef __attribute__((ext_vector_type(8))) short short8;
typedef __attribute__((ext_vector_type(4))) float f32x4;

#define PSTRIDE 4160          // partials row stride in floats (non-pow2)

// round-to-nearest-even fp32 -> bf16 bits
__device__ __forceinline__ unsigned int bf16_rn(float x) {
    unsigned int u = __float_as_uint(x);
    return (u + 0x7FFFu + ((u >> 16) & 1u)) >> 16;
}

// ---------------------------------------------------------------------------
// Kernel 1: per-row cross-entropy + logits pass-through copy.
// ---------------------------------------------------------------------------
__global__ __launch_bounds__(256) void ce_kernel(
    const float* __restrict__ logits, const int* __restrict__ target,
    float* __restrict__ out_copy, float* __restrict__ ce_rows)
{
    const int row = blockIdx.x;
    const float* x = logits + row * 1000;
    const int t = threadIdx.x;
    __shared__ float red[256];

    float m = -INFINITY;
    for (int i = t; i < 1000; i += 256) {
        float v = x[i];
        out_copy[row * 1000 + i] = v;
        m = fmaxf(m, v);
    }
    red[t] = m; __syncthreads();
    for (int s = 128; s > 0; s >>= 1) {
        if (t < s) red[t] = fmaxf(red[t], red[t + s]);
        __syncthreads();
    }
    m = red[0];
    __syncthreads();

    float ssum = 0.f;
    for (int i = t; i < 1000; i += 256) ssum += expf(x[i] - m);
    red[t] = ssum; __syncthreads();
    for (int s = 128; s > 0; s >>= 1) {
        if (t < s) red[t] += red[t + s];
        __syncthreads();
    }
    if (t == 0) {
        double lse = (double)m + log((double)red[0]);
        int tg = target[row];
        ce_rows[row] = (float)(-((double)x[tg] - lse));
    }
}

// ---------------------------------------------------------------------------
// Kernel 2 (fused repack+gram): one block per (feature, 512-k chunk).
// Grid (main path) = 3*128 + 4*64 = 640 blocks, 256 threads (4 waves).
// Phase 1: stream 64 rows x 512 k fp32 (128 KB) coalesced, cvt to bf16,
//          store to 64 KB LDS chunk [row64][k512], XOR-swizzled
//          (byte ^= (row&7)<<4) so the b128 fragment reads are conflict-free.
// Phase 2: per wave, 16 ds_read_b128 fragments + 64 MFMAs (validated layout,
//          identical k mapping: k = wave*128 + quad*8 + s*32).
// Phase 3: cross-wave reduce in LDS (reusing chunk buffer), write partials.
// Numerics identical to the previous repack+gram pipeline (same bf16_rn,
// same per-chunk MFMA accumulation order).
// ---------------------------------------------------------------------------
__global__ __launch_bounds__(256) void gramf_kernel(
    const float* __restrict__ A, const float* __restrict__ B,
    float* __restrict__ partials, int nfA, int nfB)
{
    __shared__ f32x4 ldsv[4096];            // 65536 B
    char* lds = (char*)ldsv;

    const int blk = blockIdx.x;
    const int uA = nfA * 128;               // A chunk-blocks (128 chunks/feat)
    const float* xf;
    int c, D;
    if (blk < uA) {
        int f = blk >> 7; c = blk & 127; D = 65536;
        xf = A + (size_t)f * 64 * 65536;
    } else {
        int v = blk - uA;
        int f = v >> 6; c = v & 63; D = 32768;
        xf = B + (size_t)f * 64 * 32768;
    }

    const int t = threadIdx.x;
    const int wave = t >> 6, lane = t & 63;
    const int k0 = c * 512;

    // ---- Phase 1: stage fp32 -> bf16 LDS (swizzled) ----
    // wave w owns rows [w*16, w*16+16); lane l covers k = l*8 .. l*8+7
#pragma unroll 4
    for (int rr = 0; rr < 16; ++rr) {
        const int row = wave * 16 + rr;
        const float* p = xf + (size_t)row * D + k0 + lane * 8;
        float4 va = *(const float4*)p;
        float4 vb = *(const float4*)(p + 4);
        float vv[8] = {va.x, va.y, va.z, va.w, vb.x, vb.y, vb.z, vb.w};
        short8 hv;
#pragma unroll
        for (int j = 0; j < 8; ++j) hv[j] = (short)bf16_rn(vv[j]);
        const int boff = (lane * 16) ^ ((row & 7) << 4);
        *(short8*)(lds + row * 1024 + boff) = hv;
    }
    __syncthreads();

    // ---- Phase 2: fragments + MFMA (validated layout) ----
    const int m = lane & 15, quad = lane >> 4;
    const int loff = wave * 256 + quad * 16;   // within-row byte offset

    f32x4 acc[4][4];
#pragma unroll
    for (int i = 0; i < 4; ++i)
#pragma unroll
        for (int j = 0; j < 4; ++j) acc[i][j] = (f32x4)0.f;

    short8 fr[4][4];   // [s][tm]
#pragma unroll
    for (int s = 0; s < 4; ++s)
#pragma unroll
        for (int tm = 0; tm < 4; ++tm) {
            const int row = tm * 16 + m;
            const int boff = (loff + s * 64) ^ ((row & 7) << 4);
            fr[s][tm] = *(const short8*)(lds + row * 1024 + boff);
        }
#pragma unroll
    for (int s = 0; s < 4; ++s)
#pragma unroll
        for (int tm = 0; tm < 4; ++tm)
#pragma unroll
            for (int tn = 0; tn < 4; ++tn)
                acc[tm][tn] = __builtin_amdgcn_mfma_f32_16x16x32_bf16(
                    fr[s][tm], fr[s][tn], acc[tm][tn], 0, 0, 0);

    // ---- Phase 3: cross-wave reduce in LDS (reuse chunk buffer) ----
    __syncthreads();
    float* kbuf = (float*)lds;
    if (wave == 0) {
#pragma unroll
        for (int tm = 0; tm < 4; ++tm)
#pragma unroll
            for (int tn = 0; tn < 4; ++tn)
#pragma unroll
                for (int r = 0; r < 4; ++r)
                    kbuf[(tm * 16 + quad * 4 + r) * 64 + tn * 16 + m] = acc[tm][tn][r];
    }
    __syncthreads();
    if (wave != 0) {
#pragma unroll
        for (int tm = 0; tm < 4; ++tm)
#pragma unroll
            for (int tn = 0; tn < 4; ++tn)
#pragma unroll
                for (int r = 0; r < 4; ++r)
                    atomicAdd(&kbuf[(tm * 16 + quad * 4 + r) * 64 + tn * 16 + m],
                              acc[tm][tn][r]);
    }
    __syncthreads();

    float4* outp = (float4*)(partials + (size_t)blk * PSTRIDE);
    const float4* kb4 = (const float4*)kbuf;
    for (int e = t; e < 1024; e += 256) outp[e] = kb4[e];
}

// ---------------------------------------------------------------------------
// Kernel 3: sum partials per feature -> K[f], zero diagonal.
// Main path (singleF < 0): grid 448; A features have 128 partial rows at
// base f*128, B features 64 rows at base 384+(f-3)*64.
// Fallback (singleF >= 0): grid 64, base 0, count by feature type.
// ---------------------------------------------------------------------------
__global__ __launch_bounds__(256) void reduce_kernel(
    const float* __restrict__ partials, float* __restrict__ K, int singleF)
{
    __shared__ double red[256];
    int f, eblk, base, count;
    if (singleF < 0) {
        f = blockIdx.x >> 6; eblk = blockIdx.x & 63;
        if (f < 3) { base = f * 128;            count = 128; }
        else       { base = 384 + (f - 3) * 64; count = 64;  }
    } else {
        f = singleF; eblk = blockIdx.x; base = 0;
        count = (f < 3) ? 128 : 64;
    }
    const int e = (eblk << 6) + (threadIdx.x & 63);
    const int jg = threadIdx.x >> 6;

    double s0 = 0.0, s1 = 0.0;
    for (int j = jg; j < count; j += 8) {
        s0 += (double)partials[(size_t)(base + j) * PSTRIDE + e];
        s1 += (double)partials[(size_t)(base + j + 4) * PSTRIDE + e];
    }
    red[threadIdx.x] = s0 + s1;
    __syncthreads();
    if (jg == 0) {
        double tot = red[threadIdx.x] + red[threadIdx.x + 64]
                   + red[threadIdx.x + 128] + red[threadIdx.x + 192];
        int rr = e >> 6, cc = e & 63;
        K[f * 4096 + e] = (rr == cc) ? 0.f : (float)tot;
    }
}

// ---------------------------------------------------------------------------
// Kernel 4: one block per (i,j) pair -> unbiased HSIC in fp64.
// ---------------------------------------------------------------------------
__global__ __launch_bounds__(256) void hsic_kernel(
    const float* __restrict__ K, double* __restrict__ hsic_out)
{
    const int p = blockIdx.x;
    int i, j;
    if (p < 9) { i = p / 3; j = p % 3; }
    else       { int q = p - 9; i = 3 + q / 4; j = 3 + q % 4; }
    const float* Ki = K + i * 4096;
    const float* Kj = K + j * 4096;
    const int t = threadIdx.x;

    __shared__ double red[256];
    __shared__ double ri[64], rj[64];

    double local = 0.0;
    for (int e = t; e < 4096; e += 256)
        local += (double)Ki[e] * (double)Kj[e];
    red[t] = local; __syncthreads();
    for (int s = 128; s > 0; s >>= 1) {
        if (t < s) red[t] += red[t + s];
        __syncthreads();
    }

    if (t < 64) {
        double s = 0.0;
        for (int mc = 0; mc < 64; ++mc) s += (double)Ki[t * 64 + mc];
        ri[t] = s;
    } else if (t < 128) {
        int n = t - 64;
        double s = 0.0;
        for (int mc = 0; mc < 64; ++mc) s += (double)Kj[n * 64 + mc];
        rj[n] = s;
    }
    __syncthreads();

    if (t == 0) {
        double tr = red[0];
        double rr = 0.0, si = 0.0, sj = 0.0;
        for (int n = 0; n < 64; ++n) {
            rr += ri[n] * rj[n];
            si += ri[n];
            sj += rj[n];
        }
        const double N = 64.0;
        const double c1 = (N - 1.0) * (N - 2.0);
        const double c2 = N - 2.0;
        const double c3 = N * (N - 3.0);
        hsic_out[p] = (tr + si * sj / c1 - 2.0 * rr / c2) / c3;
    }
}

// ---------------------------------------------------------------------------
// Kernel 5: combine -> loss.
// ---------------------------------------------------------------------------
__global__ __launch_bounds__(64) void final_kernel(
    const double* __restrict__ hsic, const float* __restrict__ ce_rows,
    float* __restrict__ out_loss)
{
    if (threadIdx.x != 0) return;
    double ce = 0.0;
    for (int n = 0; n < 64; ++n) ce += (double)ce_rows[n];
    ce /= 64.0;

    double cka_total = 0.0;
    for (int i = 0; i < 3; ++i)
        for (int j = 0; j < 3; ++j)
            cka_total += hsic[i * 3 + j] / sqrt(hsic[i * 3 + i] * hsic[j * 3 + j]);
    for (int i = 0; i < 4; ++i)
        for (int j = 0; j < 4; ++j)
            cka_total += hsic[9 + i * 4 + j] / sqrt(hsic[9 + i * 4 + i] * hsic[9 + j * 4 + j]);

    out_loss[0] = (float)(ce + 0.1 * cka_total);
}

// ---------------------------------------------------------------------------
extern "C" void kernel_launch(void* const* d_in, const int* in_sizes, int n_in,
                              void* d_out, int out_size, void* d_ws, size_t ws_size,
                              hipStream_t stream)
{
    const float* output  = (const float*)d_in[0];
    const int*   target  = (const int*)d_in[1];
    const float* feats_a = (const float*)d_in[2];
    const float* feats_b = (const float*)d_in[3];
    float* out = (float*)d_out;

    char* ws = (char*)d_ws;
    float*  K       = (float*)ws;                 // 114688 B
    float*  ce_rows = (float*)(ws + 114688);      // 256 B
    double* hsic    = (double*)(ws + 114944);     // 256 B
    float*  partials = (float*)(ws + 131072);

    const size_t partMain = (size_t)640 * PSTRIDE * 4;   // 10.65 MB
    const size_t mainNeed = 131072 + partMain;

    hipLaunchKernelGGL(ce_kernel, dim3(64), dim3(256), 0, stream,
                       output, target, out + 1, ce_rows);

    if (ws_size >= mainNeed) {
        // ---------------- one-shot path ----------------
        hipLaunchKernelGGL(gramf_kernel, dim3(640), dim3(256), 0, stream,
                           feats_a, feats_b, partials, 3, 4);
        hipLaunchKernelGGL(reduce_kernel, dim3(448), dim3(256), 0, stream,
                           partials, K, -1);
    } else {
        // ---------------- per-feature fallback (~2.3 MB) ----------------
        for (int f = 0; f < 7; ++f) {
            if (f < 3) {
                const float* X = feats_a + (size_t)f * 64 * 65536;
                hipLaunchKernelGGL(gramf_kernel, dim3(128), dim3(256), 0, stream,
                                   X, (const float*)nullptr, partials, 1, 0);
            } else {
                const float* X = feats_b + (size_t)(f - 3) * 64 * 32768;
                hipLaunchKernelGGL(gramf_kernel, dim3(64), dim3(256), 0, stream,
                                   (const float*)nullptr, X, partials, 0, 1);
            }
            hipLaunchKernelGGL(reduce_kernel, dim3(64), dim3(256), 0, stream,
                               partials, K, f);
        }
    }

    hipLaunchKernelGGL(hsic_kernel, dim3(25), dim3(256), 0, stream, K, hsic);
    hipLaunchKernelGGL(final_kernel, dim3(1), dim3(64), 0, stream,
                       hsic, ce_rows, out);
}

// Round 2
// 179.295 us; speedup vs baseline: 1.0155x; 1.0155x over previous
//
#include <hip/hip_runtime.h>
#include <hip/hip_bf16.h>
#include <math.h>

typedef __attribute__((ext_vector_type(8))) short short8;
typedef __attribute__((ext_vector_type(4))) float f32x4;

#define PSTRIDE 4160          // partials row stride in floats (non-pow2)

// round-to-nearest-even fp32 -> bf16 bits
__device__ __forceinline__ unsigned int bf16_rn(float x) {
    unsigned int u = __float_as_uint(x);
    return (u + 0x7FFFu + ((u >> 16) & 1u)) >> 16;
}

// ---------------------------------------------------------------------------
// Kernel 1: per-row cross-entropy + logits pass-through copy.
// ---------------------------------------------------------------------------
__global__ __launch_bounds__(256) void ce_kernel(
    const float* __restrict__ logits, const int* __restrict__ target,
    float* __restrict__ out_copy, float* __restrict__ ce_rows)
{
    const int row = blockIdx.x;
    const float* x = logits + row * 1000;
    const int t = threadIdx.x;
    __shared__ float red[256];

    float m = -INFINITY;
    for (int i = t; i < 1000; i += 256) {
        float v = x[i];
        out_copy[row * 1000 + i] = v;
        m = fmaxf(m, v);
    }
    red[t] = m; __syncthreads();
    for (int s = 128; s > 0; s >>= 1) {
        if (t < s) red[t] = fmaxf(red[t], red[t + s]);
        __syncthreads();
    }
    m = red[0];
    __syncthreads();

    float ssum = 0.f;
    for (int i = t; i < 1000; i += 256) ssum += expf(x[i] - m);
    red[t] = ssum; __syncthreads();
    for (int s = 128; s > 0; s >>= 1) {
        if (t < s) red[t] += red[t + s];
        __syncthreads();
    }
    if (t == 0) {
        double lse = (double)m + log((double)red[0]);
        int tg = target[row];
        ce_rows[row] = (float)(-((double)x[tg] - lse));
    }
}

// ---------------------------------------------------------------------------
// Kernel 2 (fused, DMA-staged): one block per (feature, 512-k chunk).
// Grid (main path) = 3*128 + 4*64 = 640 blocks, 256 threads (4 waves).
//
// Per 512-k chunk, two sub-rounds of 256 fp32 k each:
//   Stage: 64 rows x 1 KB via global_load_lds dwordx4 (1 instr/row, 16/wave,
//          all in flight -> 128 KB outstanding per CU; this is the Little's-law
//          fix for the 770 GB/s plateau). LDS dest linear; XOR swizzle
//          (row&7)<<4 applied to the per-lane GLOBAL source (16B granules
//          within 128B windows) so fragment reads are conflict-light.
//   Compute: wave w owns k-window [w*64, w*64+64): per 32-k step read 4
//          fp32 fragments (2x ds_read_b128, XOR'd addr), convert bf16_rn
//          in-register, 16 MFMAs (validated 16x16x32 layout).
// Cross-wave reduce + partials write unchanged (validated).
// ---------------------------------------------------------------------------
__global__ __launch_bounds__(256) void gramf_kernel(
    const float* __restrict__ A, const float* __restrict__ B,
    float* __restrict__ partials, int nfA, int nfB)
{
    __shared__ float lbuf[16384];          // 64 KB: [64 rows][256 fp32]
    const int blk = blockIdx.x;
    const int uA = nfA * 128;              // A chunk-blocks (128 chunks/feat)
    const float* xf;
    int c, D;
    if (blk < uA) {
        int f = blk >> 7; c = blk & 127; D = 65536;
        xf = A + (size_t)f * 64 * 65536;
    } else {
        int v = blk - uA;
        int f = v >> 6; c = v & 63; D = 32768;
        xf = B + (size_t)f * 64 * 32768;
    }

    const int t = threadIdx.x;
    const int wave = t >> 6, lane = t & 63;
    const int m = lane & 15, quad = lane >> 4;

    f32x4 acc[4][4];
#pragma unroll
    for (int i = 0; i < 4; ++i)
#pragma unroll
        for (int j = 0; j < 4; ++j) acc[i][j] = (f32x4)0.f;

    for (int h = 0; h < 2; ++h) {
        const int k0 = c * 512 + h * 256;     // fp32 element offset this round
        if (h) __syncthreads();               // lbuf reads of prev round done

        // ---- stage: wave w DMAs rows [w*16, w*16+16), 1 KB each ----
#pragma unroll
        for (int rr = 0; rr < 16; ++rr) {
            const int row = wave * 16 + rr;
            const int gb = (lane * 16) ^ ((row & 7) << 4);   // byte in row
            const float* src = xf + (size_t)row * D + k0 + (gb >> 2);
            __builtin_amdgcn_global_load_lds(
                (const __attribute__((address_space(1))) void*)src,
                (__attribute__((address_space(3))) void*)&lbuf[row * 256],
                16, 0, 0);
        }
        asm volatile("s_waitcnt vmcnt(0)" ::: "memory");
        __syncthreads();

        // ---- compute: 2 k-steps of 32 within this wave's 64-k window ----
#pragma unroll
        for (int s = 0; s < 2; ++s) {
            short8 fr[4];
#pragma unroll
            for (int tt = 0; tt < 4; ++tt) {
                const int row = tt * 16 + m;
                const int col = (wave * 64 + s * 32 + quad * 8) * 4; // byte
                const int sw = (row & 7) << 4;
                const char* rb = (const char*)&lbuf[row * 256];
                float4 a = *(const float4*)(rb + (col ^ sw));
                float4 b = *(const float4*)(rb + ((col + 16) ^ sw));
                short8 hv;
                hv[0] = (short)bf16_rn(a.x); hv[1] = (short)bf16_rn(a.y);
                hv[2] = (short)bf16_rn(a.z); hv[3] = (short)bf16_rn(a.w);
                hv[4] = (short)bf16_rn(b.x); hv[5] = (short)bf16_rn(b.y);
                hv[6] = (short)bf16_rn(b.z); hv[7] = (short)bf16_rn(b.w);
                fr[tt] = hv;
            }
#pragma unroll
            for (int tm = 0; tm < 4; ++tm)
#pragma unroll
                for (int tn = 0; tn < 4; ++tn)
                    acc[tm][tn] = __builtin_amdgcn_mfma_f32_16x16x32_bf16(
                        fr[tm], fr[tn], acc[tm][tn], 0, 0, 0);
        }
    }

    // ---- cross-wave reduce in LDS (C layout validated R2-R4) ----
    __syncthreads();
    float* kbuf = (float*)lbuf;
    if (wave == 0) {
#pragma unroll
        for (int tm = 0; tm < 4; ++tm)
#pragma unroll
            for (int tn = 0; tn < 4; ++tn)
#pragma unroll
                for (int r = 0; r < 4; ++r)
                    kbuf[(tm * 16 + quad * 4 + r) * 64 + tn * 16 + m] = acc[tm][tn][r];
    }
    __syncthreads();
    if (wave != 0) {
#pragma unroll
        for (int tm = 0; tm < 4; ++tm)
#pragma unroll
            for (int tn = 0; tn < 4; ++tn)
#pragma unroll
                for (int r = 0; r < 4; ++r)
                    atomicAdd(&kbuf[(tm * 16 + quad * 4 + r) * 64 + tn * 16 + m],
                              acc[tm][tn][r]);
    }
    __syncthreads();

    float4* outp = (float4*)(partials + (size_t)blk * PSTRIDE);
    const float4* kb4 = (const float4*)kbuf;
    for (int e = t; e < 1024; e += 256) outp[e] = kb4[e];
}

// ---------------------------------------------------------------------------
// Kernel 3: sum partials per feature -> K[f], zero diagonal.
// Main path (singleF < 0): grid 448; A features have 128 partial rows at
// base f*128, B features 64 rows at base 384+(f-3)*64.
// Fallback (singleF >= 0): grid 64, base 0, count by feature type.
// ---------------------------------------------------------------------------
__global__ __launch_bounds__(256) void reduce_kernel(
    const float* __restrict__ partials, float* __restrict__ K, int singleF)
{
    __shared__ double red[256];
    int f, eblk, base, count;
    if (singleF < 0) {
        f = blockIdx.x >> 6; eblk = blockIdx.x & 63;
        if (f < 3) { base = f * 128;            count = 128; }
        else       { base = 384 + (f - 3) * 64; count = 64;  }
    } else {
        f = singleF; eblk = blockIdx.x; base = 0;
        count = (f < 3) ? 128 : 64;
    }
    const int e = (eblk << 6) + (threadIdx.x & 63);
    const int jg = threadIdx.x >> 6;

    double s0 = 0.0, s1 = 0.0;
    for (int j = jg; j < count; j += 8) {
        s0 += (double)partials[(size_t)(base + j) * PSTRIDE + e];
        s1 += (double)partials[(size_t)(base + j + 4) * PSTRIDE + e];
    }
    red[threadIdx.x] = s0 + s1;
    __syncthreads();
    if (jg == 0) {
        double tot = red[threadIdx.x] + red[threadIdx.x + 64]
                   + red[threadIdx.x + 128] + red[threadIdx.x + 192];
        int rr = e >> 6, cc = e & 63;
        K[f * 4096 + e] = (rr == cc) ? 0.f : (float)tot;
    }
}

// ---------------------------------------------------------------------------
// Kernel 4: one block per (i,j) pair -> unbiased HSIC in fp64.
// ---------------------------------------------------------------------------
__global__ __launch_bounds__(256) void hsic_kernel(
    const float* __restrict__ K, double* __restrict__ hsic_out)
{
    const int p = blockIdx.x;
    int i, j;
    if (p < 9) { i = p / 3; j = p % 3; }
    else       { int q = p - 9; i = 3 + q / 4; j = 3 + q % 4; }
    const float* Ki = K + i * 4096;
    const float* Kj = K + j * 4096;
    const int t = threadIdx.x;

    __shared__ double red[256];
    __shared__ double ri[64], rj[64];

    double local = 0.0;
    for (int e = t; e < 4096; e += 256)
        local += (double)Ki[e] * (double)Kj[e];
    red[t] = local; __syncthreads();
    for (int s = 128; s > 0; s >>= 1) {
        if (t < s) red[t] += red[t + s];
        __syncthreads();
    }

    if (t < 64) {
        double s = 0.0;
        for (int mc = 0; mc < 64; ++mc) s += (double)Ki[t * 64 + mc];
        ri[t] = s;
    } else if (t < 128) {
        int n = t - 64;
        double s = 0.0;
        for (int mc = 0; mc < 64; ++mc) s += (double)Kj[n * 64 + mc];
        rj[n] = s;
    }
    __syncthreads();

    if (t == 0) {
        double tr = red[0];
        double rr = 0.0, si = 0.0, sj = 0.0;
        for (int n = 0; n < 64; ++n) {
            rr += ri[n] * rj[n];
            si += ri[n];
            sj += rj[n];
        }
        const double N = 64.0;
        const double c1 = (N - 1.0) * (N - 2.0);
        const double c2 = N - 2.0;
        const double c3 = N * (N - 3.0);
        hsic_out[p] = (tr + si * sj / c1 - 2.0 * rr / c2) / c3;
    }
}

// ---------------------------------------------------------------------------
// Kernel 5: combine -> loss.
// ---------------------------------------------------------------------------
__global__ __launch_bounds__(64) void final_kernel(
    const double* __restrict__ hsic, const float* __restrict__ ce_rows,
    float* __restrict__ out_loss)
{
    if (threadIdx.x != 0) return;
    double ce = 0.0;
    for (int n = 0; n < 64; ++n) ce += (double)ce_rows[n];
    ce /= 64.0;

    double cka_total = 0.0;
    for (int i = 0; i < 3; ++i)
        for (int j = 0; j < 3; ++j)
            cka_total += hsic[i * 3 + j] / sqrt(hsic[i * 3 + i] * hsic[j * 3 + j]);
    for (int i = 0; i < 4; ++i)
        for (int j = 0; j < 4; ++j)
            cka_total += hsic[9 + i * 4 + j] / sqrt(hsic[9 + i * 4 + i] * hsic[9 + j * 4 + j]);

    out_loss[0] = (float)(ce + 0.1 * cka_total);
}

// ---------------------------------------------------------------------------
extern "C" void kernel_launch(void* const* d_in, const int* in_sizes, int n_in,
                              void* d_out, int out_size, void* d_ws, size_t ws_size,
                              hipStream_t stream)
{
    const float* output  = (const float*)d_in[0];
    const int*   target  = (const int*)d_in[1];
    const float* feats_a = (const float*)d_in[2];
    const float* feats_b = (const float*)d_in[3];
    float* out = (float*)d_out;

    char* ws = (char*)d_ws;
    float*  K       = (float*)ws;                 // 114688 B
    float*  ce_rows = (float*)(ws + 114688);      // 256 B
    double* hsic    = (double*)(ws + 114944);     // 256 B
    float*  partials = (float*)(ws + 131072);

    const size_t partMain = (size_t)640 * PSTRIDE * 4;   // 10.65 MB
    const size_t mainNeed = 131072 + partMain;

    hipLaunchKernelGGL(ce_kernel, dim3(64), dim3(256), 0, stream,
                       output, target, out + 1, ce_rows);

    if (ws_size >= mainNeed) {
        // ---------------- one-shot path ----------------
        hipLaunchKernelGGL(gramf_kernel, dim3(640), dim3(256), 0, stream,
                           feats_a, feats_b, partials, 3, 4);
        hipLaunchKernelGGL(reduce_kernel, dim3(448), dim3(256), 0, stream,
                           partials, K, -1);
    } else {
        // ---------------- per-feature fallback (~2.3 MB) ----------------
        for (int f = 0; f < 7; ++f) {
            if (f < 3) {
                const float* X = feats_a + (size_t)f * 64 * 65536;
                hipLaunchKernelGGL(gramf_kernel, dim3(128), dim3(256), 0, stream,
                                   X, (const float*)nullptr, partials, 1, 0);
            } else {
                const float* X = feats_b + (size_t)(f - 3) * 64 * 32768;
                hipLaunchKernelGGL(gramf_kernel, dim3(64), dim3(256), 0, stream,
                                   (const float*)nullptr, X, partials, 0, 1);
            }
            hipLaunchKernelGGL(reduce_kernel, dim3(64), dim3(256), 0, stream,
                               partials, K, f);
        }
    }

    hipLaunchKernelGGL(hsic_kernel, dim3(25), dim3(256), 0, stream, K, hsic);
    hipLaunchKernelGGL(final_kernel, dim3(1), dim3(64), 0, stream,
                       hsic, ce_rows, out);
}